// Round 1
// baseline (62.265 us; speedup 1.0000x reference)
//
#include <hip/hip_runtime.h>

#define BSZ 512
#define KOUT 960
// e^{+19.3}, e^{-19.3}: exp-domain images of the reference's LLR clip.
#define EMAX 2.4092698e8f
#define EMIN 4.1506346e-9f

// Exp-domain boxplus: (1 + Ex*Ey)/(Ex+Ey), args clamped to the clip range.
__device__ __forceinline__ float boxpE(float ex, float ey) {
    ex = fminf(fmaxf(ex, EMIN), EMAX);
    ey = fminf(fmaxf(ey, EMIN), EMAX);
    float num = __builtin_fmaf(ex, ey, 1.0f);
    return num * __builtin_amdgcn_rcpf(ex + ey);
}
// Args provably within [EMIN, EMAX] (boxpE-output closure) -> clamps elided.
__device__ __forceinline__ float boxpE_nc(float ex, float ey) {
    float num = __builtin_fmaf(ex, ey, 1.0f);
    return num * __builtin_amdgcn_rcpf(ex + ey);
}

// Lane-xor exchange. Masks 1,2: DPP quad_perm (VALU pipe, ~10cy, off the LDS
// critical path). Masks 4..32: ds_bpermute via __shfl_xor (index hoisted by
// the compiler; one LDS-pipe op per use).
__device__ __forceinline__ float shx(float v, int m) {
    if (m == 1)
        return __int_as_float(__builtin_amdgcn_update_dpp(
            0, __float_as_int(v), 0xB1 /*quad_perm [1,0,3,2]*/, 0xF, 0xF, true));
    if (m == 2)
        return __int_as_float(__builtin_amdgcn_update_dpp(
            0, __float_as_int(v), 0x4E /*quad_perm [2,3,0,1]*/, 0xF, 0xF, true));
    return __shfl_xor(v, m, 64);
}

// Single-wave layout: position p = j*64 + lane, j = 0..15, lane = 0..63.
// Every stage distance 2^s with s>=6 is an intra-lane j-xor (registers);
// s<=5 is a lane-xor (shfl). No __syncthreads, no LDS anywhere.
// R sparsity: supp r[1..6]=[0,64) (j=0 slice), r[7]=[0,128) (j<2),
// r[8]=[0,256) (j<4), r[9]=[0,512) (j<8).
// Backward restarts from llr each iteration and a-side r-terms vanish on the
// support, so L[9][<512], L[8][<256], L[7][<128], L[6][<64] are
// ITERATION-INVARIANT -> prologue (pure intra-lane VALU now).
// Per-iteration work is the 64-lane recurrence: fwd r[1..6] (6 boxp, shx) +
// bwd L[5..1] (5 boxp, shx). Iteration 9 runs the full pipeline for b-sides.
__global__ __launch_bounds__(64, 1) void polar_bp(const float* __restrict__ in,
                                                  float* __restrict__ out) {
    const int lane = threadIdx.x;
    const float* inb = in + (size_t)blockIdx.x * 1024;

    float e[16];
#pragma unroll
    for (int j = 0; j < 16; ++j) e[j] = __expf(-inb[j * 64 + lane]);

    // ---- prologue: iteration-invariant a-side backward chain (intra-lane) ----
    float L9[8], L8[4], L7[2];
#pragma unroll
    for (int j = 0; j < 8; ++j) L9[j] = boxpE(e[j], e[j + 8]);      // L[9][p<512]
#pragma unroll
    for (int j = 0; j < 4; ++j) L8[j] = boxpE_nc(L9[j], L9[j + 4]); // L[8][p<256]
#pragma unroll
    for (int j = 0; j < 2; ++j) L7[j] = boxpE_nc(L8[j], L8[j + 2]); // L[7][p<128]
    const float Li6 = boxpE_nc(L7[0], L7[1]);                       // L[6][p<64]

    // ---- recurrence: iters 0..8 full, iter 9 forward only (j=0 slice) ----
    float Rs[6], r6;
    float Ls[7];
#pragma unroll
    for (int s = 0; s < 7; ++s) Ls[s] = 1.f;  // msg_l0 = zeros
#pragma unroll 1
    for (int it = 0; it < 10; ++it) {
        // forward chain r[1]..r[6]
        float r = EMAX;  // r[0] = LLRMAX on frozen set
#pragma unroll
        for (int s = 0; s <= 5; ++s) {
            float lp = shx(Ls[s + 1], 1 << s);
            float rp = shx(r, 1 << s);
            bool isB = (lane >> s) & 1;
            float x = isB ? rp : r;   // a: boxp(r, lp*rp); b: boxp(rp,lp)*r
            float y = isB ? lp : lp * rp;
            float c = boxpE(x, y);
            r = isB ? c * r : c;
            if (s <= 4) Rs[s + 1] = r;
        }
        if (it == 9) { r6 = r; break; }  // final fwd feeds the full pass
        // backward stages 5..1 from invariant L[6]
        float Lc = Li6;
#pragma unroll
        for (int s = 5; s >= 1; --s) {
            const int m = 1 << s;
            float rp = shx(Rs[s], m);
            float lp = shx(Lc, m);
            bool isB = (lane >> s) & 1;
            float x = isB ? rp : Lc;
            float y = isB ? lp : lp * rp;
            float c = boxpE(x, y);
            Lc = isB ? c * Lc : c;
            Ls[s] = Lc;
        }
        Ls[6] = Li6;
    }

    // ---- final iteration, full pipeline (intra-lane in j) ----
    // r-chain broadcasts: r_{s+1}[p] = boxp(r_s[p mod 2^s], L_{s+1}[p ^ 2^s])
    float r7v[2], r8v[4], r9v[8];
#pragma unroll
    for (int t = 0; t < 2; ++t) r7v[t] = boxpE(r6, L7[t ^ 1]);
#pragma unroll
    for (int t = 0; t < 4; ++t) r8v[t] = boxpE(r7v[t & 1], L8[t ^ 2]);
#pragma unroll
    for (int t = 0; t < 8; ++t) r9v[t] = boxpE(r8v[t & 3], L9[t ^ 4]);

    // stage 9 (j ^ 8): a-sides are the invariant L9; b-sides get the r-term
    float Lc[16];
#pragma unroll
    for (int j = 0; j < 8; ++j) Lc[j] = L9[j];
#pragma unroll
    for (int j = 8; j < 16; ++j) Lc[j] = boxpE(r9v[j - 8], e[j - 8]) * e[j];

    // stage 8 (j ^ 4); r[8] support j<4 => b-sides j in [4,8) carry r, rest no-op
    float t8[16];
#pragma unroll
    for (int j = 0; j < 16; ++j) {
        float Lp = Lc[j ^ 4];
        if (!(j & 4))      t8[j] = boxpE(Lc[j], Lp);
        else if (j < 8)    t8[j] = boxpE(r8v[j - 4], Lp) * Lc[j];
        else               t8[j] = Lc[j];  // boxp(0,x)=0 -> exact no-op
    }
    // stage 7 (j ^ 2)
    float t7[16];
#pragma unroll
    for (int j = 0; j < 16; ++j) {
        float Lp = t8[j ^ 2];
        if (!(j & 2))      t7[j] = boxpE(t8[j], Lp);
        else if (j < 4)    t7[j] = boxpE(r7v[j - 2], Lp) * t8[j];
        else               t7[j] = t8[j];
    }
    // stage 6 (j ^ 1)
#pragma unroll
    for (int j = 0; j < 16; ++j) {
        float Lp = t7[j ^ 1];
        if (!(j & 1))      Lc[j] = boxpE(t7[j], Lp);
        else if (j == 1)   Lc[j] = boxpE(r6, Lp) * t7[j];
        else               Lc[j] = t7[j];
    }

    // stages 5..1 (lane shuffles); Rs hold final-iteration values.
    // j=0 is the r-support slice; j>=1: b-side is an exact no-op, a-side is
    // plain boxp with the partner.
#pragma unroll
    for (int s = 5; s >= 1; --s) {
        const int m = 1 << s;
        float rp = shx(Rs[s], m);
        bool isB = (lane >> s) & 1;
        {
            float lp = shx(Lc[0], m);
            float x = isB ? rp : Lc[0];
            float y = isB ? lp : lp * rp;
            float c = boxpE(x, y);
            Lc[0] = isB ? c * Lc[0] : c;
        }
#pragma unroll
        for (int j = 1; j < 16; ++j) {
            float lp = shx(Lc[j], m);
            float c = boxpE(Lc[j], lp);
            Lc[j] = isB ? Lc[j] : c;
        }
    }

    // ---- stage 0 -> output. p>=64 have r1=r2=0:
    // even p: -boxp(l1,l2); odd p: -l2. One v_log back to log domain.
    const size_t ob = (size_t)blockIdx.x * KOUT;
    const bool odd = lane & 1;
#pragma unroll
    for (int j = 1; j < 16; ++j) {
        float lp = shx(Lc[j], 1);
        float ev = odd ? Lc[j] : boxpE(Lc[j], lp);
        out[ob + j * 64 + lane - 64] = -__logf(ev);
    }
}

extern "C" void kernel_launch(void* const* d_in, const int* in_sizes, int n_in,
                              void* d_out, int out_size, void* d_ws, size_t ws_size,
                              hipStream_t stream) {
    const float* in = (const float*)d_in[0];
    float* out = (float*)d_out;
    polar_bp<<<BSZ, 64, 0, stream>>>(in, out);
}